// Round 1
// baseline (188.831 us; speedup 1.0000x reference)
//
#include <hip/hip_runtime.h>
#include <hip/hip_bf16.h>

typedef __bf16 bf16;
typedef __attribute__((ext_vector_type(8))) __bf16 bf16x8;
typedef __attribute__((ext_vector_type(4))) float f32x4;

// Problem constants
// B=4, S=2048, H=8, D=64, C=512, M=B*S=8192
#define SEQ   2048
#define HEADS 8
#define DHEAD 64
#define CDIM  512
#define MROWS 8192
#define SCALE 0.125f

// ---------------------------------------------------------------------------
// 1) hs fp32 -> bf16
__global__ __launch_bounds__(256) void k_cvt_hs(const float* __restrict__ in,
                                                bf16* __restrict__ out) {
    int idx = blockIdx.x * 256 + threadIdx.x;           // 524288 threads, 8 elems each
    const float4* in4 = reinterpret_cast<const float4*>(in);
    float4 a = in4[idx * 2], b = in4[idx * 2 + 1];
    bf16x8 o;
    o[0] = (bf16)a.x; o[1] = (bf16)a.y; o[2] = (bf16)a.z; o[3] = (bf16)a.w;
    o[4] = (bf16)b.x; o[5] = (bf16)b.y; o[6] = (bf16)b.z; o[7] = (bf16)b.w;
    reinterpret_cast<bf16x8*>(out)[idx] = o;
}

// ---------------------------------------------------------------------------
// 2) weight transpose+convert: W[fin][fout] f32 -> Wt[fout][fin] bf16 (4 mats)
__global__ __launch_bounds__(256) void k_wtrans(const float* __restrict__ w0,
                                                const float* __restrict__ w1,
                                                const float* __restrict__ w2,
                                                const float* __restrict__ w3,
                                                bf16* __restrict__ wt) {
    const float* w = blockIdx.z == 0 ? w0 : blockIdx.z == 1 ? w1 : blockIdx.z == 2 ? w2 : w3;
    bf16* out = wt + (size_t)blockIdx.z * CDIM * CDIM;
    __shared__ bf16 tile[64][65];
    const int t = threadIdx.x;
    const int r0 = blockIdx.x * 64, c0 = blockIdx.y * 64;
    const int r = t >> 2, cc = (t & 3) * 16;
    const float4* src = reinterpret_cast<const float4*>(w + (size_t)(r0 + r) * CDIM + c0 + cc);
#pragma unroll
    for (int v = 0; v < 4; ++v) {
        float4 f = src[v];
        tile[r][cc + v * 4 + 0] = (bf16)f.x;
        tile[r][cc + v * 4 + 1] = (bf16)f.y;
        tile[r][cc + v * 4 + 2] = (bf16)f.z;
        tile[r][cc + v * 4 + 3] = (bf16)f.w;
    }
    __syncthreads();
    bf16x8 o0, o1;
#pragma unroll
    for (int j = 0; j < 8; ++j) { o0[j] = tile[cc + j][r]; o1[j] = tile[cc + 8 + j][r]; }
    bf16* dst = out + (size_t)(c0 + r) * CDIM + r0 + cc;
    *reinterpret_cast<bf16x8*>(dst) = o0;
    *reinterpret_cast<bf16x8*>(dst + 8) = o1;
}

// ---------------------------------------------------------------------------
// 3) QKV GEMM: A[8192][512]bf16 x Wt[512][512]bf16 -> {Q,K,V}[B][H][S][D] bf16
//    128x128 tile, BK=32, 4 waves (2x2), each wave 64x64 (4x4 of 16x16x32)
__global__ __launch_bounds__(256) void k_gemm_qkv(const bf16* __restrict__ A,
                                                  const bf16* __restrict__ Wt,
                                                  bf16* __restrict__ Qb,
                                                  bf16* __restrict__ Kb,
                                                  bf16* __restrict__ Vb) {
    __shared__ __align__(16) bf16 As[128 * 32];
    __shared__ __align__(16) bf16 Bs[128 * 32];
    const int t = threadIdx.x, lane = t & 63, wid = t >> 6;
    const int wr = wid >> 1, wc = wid & 1;
    const int g = (lane >> 4) & 3, q = lane & 15;
    const int m0 = blockIdx.x * 128, n0 = blockIdx.y * 128;
    const bf16* Bmat = Wt + (size_t)blockIdx.z * CDIM * CDIM;
    f32x4 acc[4][4] = {};
    const int sr = t >> 1, sc = (t & 1) * 16;
    for (int kt = 0; kt < 16; ++kt) {
        const int k0 = kt * 32;
        const bf16x8* a_src = reinterpret_cast<const bf16x8*>(A + (size_t)(m0 + sr) * CDIM + k0 + sc);
        const bf16x8* b_src = reinterpret_cast<const bf16x8*>(Bmat + (size_t)(n0 + sr) * CDIM + k0 + sc);
        bf16x8 av0 = a_src[0], av1 = a_src[1];
        bf16x8 bv0 = b_src[0], bv1 = b_src[1];
        __syncthreads();
        *reinterpret_cast<bf16x8*>(&As[sr * 32 + sc]) = av0;
        *reinterpret_cast<bf16x8*>(&As[sr * 32 + sc + 8]) = av1;
        *reinterpret_cast<bf16x8*>(&Bs[sr * 32 + sc]) = bv0;
        *reinterpret_cast<bf16x8*>(&Bs[sr * 32 + sc + 8]) = bv1;
        __syncthreads();
        bf16x8 af[4], bfv[4];
#pragma unroll
        for (int m = 0; m < 4; ++m)
            af[m] = *reinterpret_cast<const bf16x8*>(&As[(wr * 64 + m * 16 + q) * 32 + g * 8]);
#pragma unroll
        for (int n = 0; n < 4; ++n)
            bfv[n] = *reinterpret_cast<const bf16x8*>(&Bs[(wc * 64 + n * 16 + q) * 32 + g * 8]);
#pragma unroll
        for (int m = 0; m < 4; ++m)
#pragma unroll
            for (int n = 0; n < 4; ++n)
                acc[m][n] = __builtin_amdgcn_mfma_f32_16x16x32_bf16(af[m], bfv[n], acc[m][n], 0, 0, 0);
    }
    bf16* outp = blockIdx.z == 0 ? Qb : (blockIdx.z == 1 ? Kb : Vb);
#pragma unroll
    for (int m = 0; m < 4; ++m) {
        const int rbase = m0 + wr * 64 + m * 16 + g * 4;
#pragma unroll
        for (int i = 0; i < 4; ++i) {
            const int row = rbase + i;
            const int b = row >> 11, s = row & 2047;
#pragma unroll
            for (int n = 0; n < 4; ++n) {
                const int col = n0 + wc * 64 + n * 16 + q;
                const int h = col >> 6, d = col & 63;
                outp[((((size_t)b * HEADS + h) * SEQ + s) << 6) + d] = (bf16)acc[m][n][i];
            }
        }
    }
}

// ---------------------------------------------------------------------------
// 4) V transpose: [B][H][S][D] -> [B][H][D][S]
__global__ __launch_bounds__(256) void k_vtrans(const bf16* __restrict__ V,
                                                bf16* __restrict__ Vt) {
    __shared__ bf16 tile[64][65];
    const int t = threadIdx.x;
    const int s0 = blockIdx.x * 64;
    const size_t bh = blockIdx.y;
    const int r = t >> 2, cc = (t & 3) * 16;
    const bf16x8* src = reinterpret_cast<const bf16x8*>(V + (bh * SEQ + s0 + r) * DHEAD + cc);
    bf16x8 v0 = src[0], v1 = src[1];
#pragma unroll
    for (int j = 0; j < 8; ++j) { tile[r][cc + j] = v0[j]; tile[r][cc + 8 + j] = v1[j]; }
    __syncthreads();
    bf16x8 o0, o1;
#pragma unroll
    for (int j = 0; j < 8; ++j) { o0[j] = tile[cc + j][r]; o1[j] = tile[cc + 8 + j][r]; }
    bf16* dst = Vt + (bh * DHEAD + r) * SEQ + s0 + cc;
    *reinterpret_cast<bf16x8*>(dst) = o0;
    *reinterpret_cast<bf16x8*>(dst + 8) = o1;
}

// ---------------------------------------------------------------------------
// 5) Flash attention. 4 waves x 16 q-rows, KVBLK=64. Swapped QK^T:
//    S^T = mfma(K, Q) -> each lane owns one q (= lane&15); softmax reduce is
//    shfl_xor(16), shfl_xor(32). PV as O^T = mfma(V^T, P^T).
//    Output O in [B][S][H*D] bf16 for the final GEMM.
__global__ __launch_bounds__(256) void k_attn(const bf16* __restrict__ Qg,
                                              const bf16* __restrict__ Kg,
                                              const bf16* __restrict__ Vtg,
                                              bf16* __restrict__ Og) {
    __shared__ __align__(16) bf16 K_lds[64 * 72];
    __shared__ __align__(16) bf16 Vt_lds[64 * 72];
    __shared__ __align__(16) bf16 P_lds[4][16 * 72];
    const int t = threadIdx.x, lane = t & 63, wid = t >> 6;
    const int g = (lane >> 4) & 3, q = lane & 15;
    const size_t bh = blockIdx.y;
    const int q0 = blockIdx.x * 64 + wid * 16;
    const int b = (int)(bh >> 3), h = (int)(bh & 7);

    bf16x8 qf[2];
#pragma unroll
    for (int ks = 0; ks < 2; ++ks)
        qf[ks] = *reinterpret_cast<const bf16x8*>(Qg + (bh * SEQ + q0 + q) * DHEAD + ks * 32 + g * 8);

    f32x4 accO[4] = {};
    float m_run = -1e30f, l_run = 0.f;
    const int sr = t >> 2, scc = (t & 3) * 16;

    for (int kt = 0; kt < 32; ++kt) {
        const int kv0 = kt * 64;
        const bf16x8* ksrc = reinterpret_cast<const bf16x8*>(Kg + (bh * SEQ + kv0 + sr) * DHEAD + scc);
        const bf16x8* vsrc = reinterpret_cast<const bf16x8*>(Vtg + (bh * DHEAD + sr) * SEQ + kv0 + scc);
        bf16x8 kva = ksrc[0], kvb = ksrc[1];
        bf16x8 vva = vsrc[0], vvb = vsrc[1];
        __syncthreads();                       // prior tile's LDS reads complete
        *reinterpret_cast<bf16x8*>(&K_lds[sr * 72 + scc]) = kva;
        *reinterpret_cast<bf16x8*>(&K_lds[sr * 72 + scc + 8]) = kvb;
        *reinterpret_cast<bf16x8*>(&Vt_lds[sr * 72 + scc]) = vva;
        *reinterpret_cast<bf16x8*>(&Vt_lds[sr * 72 + scc + 8]) = vvb;
        __syncthreads();

        // QK^T (swapped): st[m] = K[m-tile] x Q^T   -> C[kv][q]
        f32x4 st[4] = {};
#pragma unroll
        for (int ks = 0; ks < 2; ++ks) {
            bf16x8 qk = qf[ks];
#pragma unroll
            for (int m = 0; m < 4; ++m) {
                bf16x8 kf = *reinterpret_cast<const bf16x8*>(&K_lds[(m * 16 + q) * 72 + ks * 32 + g * 8]);
                st[m] = __builtin_amdgcn_mfma_f32_16x16x32_bf16(kf, qk, st[m], 0, 0, 0);
            }
        }

        // online softmax over this tile's 64 kv
        float sc[4][4];
        float tmax = -1e30f;
#pragma unroll
        for (int m = 0; m < 4; ++m)
#pragma unroll
            for (int i = 0; i < 4; ++i) {
                sc[m][i] = st[m][i] * SCALE;
                tmax = fmaxf(tmax, sc[m][i]);
            }
        tmax = fmaxf(tmax, __shfl_xor(tmax, 16));
        tmax = fmaxf(tmax, __shfl_xor(tmax, 32));
        const float mnew = fmaxf(m_run, tmax);
        const float alpha = __expf(m_run - mnew);
        float psum = 0.f;
#pragma unroll
        for (int m = 0; m < 4; ++m)
#pragma unroll
            for (int i = 0; i < 4; ++i) {
                float p = __expf(sc[m][i] - mnew);
                psum += p;
                P_lds[wid][q * 72 + m * 16 + g * 4 + i] = (bf16)p;   // P[q][kv]
            }
        psum += __shfl_xor(psum, 16);
        psum += __shfl_xor(psum, 32);
        l_run = l_run * alpha + psum;
        m_run = mnew;
#pragma unroll
        for (int m = 0; m < 4; ++m)
#pragma unroll
            for (int i = 0; i < 4; ++i) accO[m][i] *= alpha;

        // PV: O^T += V^T x P^T
#pragma unroll
        for (int ks = 0; ks < 2; ++ks) {
            bf16x8 pb = *reinterpret_cast<const bf16x8*>(&P_lds[wid][q * 72 + ks * 32 + g * 8]);
#pragma unroll
            for (int m = 0; m < 4; ++m) {
                bf16x8 vf = *reinterpret_cast<const bf16x8*>(&Vt_lds[(m * 16 + q) * 72 + ks * 32 + g * 8]);
                accO[m] = __builtin_amdgcn_mfma_f32_16x16x32_bf16(vf, pb, accO[m], 0, 0, 0);
            }
        }
    }

    const float inv = 1.0f / l_run;
#pragma unroll
    for (int m = 0; m < 4; ++m)
#pragma unroll
        for (int i = 0; i < 4; ++i) {
            const int d = m * 16 + g * 4 + i;
            Og[((size_t)b * SEQ + q0 + q) * (HEADS * DHEAD) + h * DHEAD + d] = (bf16)(accO[m][i] * inv);
        }
}

// ---------------------------------------------------------------------------
// 6) Output GEMM: O[8192][512]bf16 x Wo_t[512][512]bf16 -> out[8192][512] f32
__global__ __launch_bounds__(256) void k_gemm_o(const bf16* __restrict__ A,
                                                const bf16* __restrict__ Bt,
                                                float* __restrict__ out) {
    __shared__ __align__(16) bf16 As[128 * 32];
    __shared__ __align__(16) bf16 Bs[128 * 32];
    const int t = threadIdx.x, lane = t & 63, wid = t >> 6;
    const int wr = wid >> 1, wc = wid & 1;
    const int g = (lane >> 4) & 3, q = lane & 15;
    const int m0 = blockIdx.x * 128, n0 = blockIdx.y * 128;
    f32x4 acc[4][4] = {};
    const int sr = t >> 1, sc = (t & 1) * 16;
    for (int kt = 0; kt < 16; ++kt) {
        const int k0 = kt * 32;
        const bf16x8* a_src = reinterpret_cast<const bf16x8*>(A + (size_t)(m0 + sr) * CDIM + k0 + sc);
        const bf16x8* b_src = reinterpret_cast<const bf16x8*>(Bt + (size_t)(n0 + sr) * CDIM + k0 + sc);
        bf16x8 av0 = a_src[0], av1 = a_src[1];
        bf16x8 bv0 = b_src[0], bv1 = b_src[1];
        __syncthreads();
        *reinterpret_cast<bf16x8*>(&As[sr * 32 + sc]) = av0;
        *reinterpret_cast<bf16x8*>(&As[sr * 32 + sc + 8]) = av1;
        *reinterpret_cast<bf16x8*>(&Bs[sr * 32 + sc]) = bv0;
        *reinterpret_cast<bf16x8*>(&Bs[sr * 32 + sc + 8]) = bv1;
        __syncthreads();
        bf16x8 af[4], bfv[4];
#pragma unroll
        for (int m = 0; m < 4; ++m)
            af[m] = *reinterpret_cast<const bf16x8*>(&As[(wr * 64 + m * 16 + q) * 32 + g * 8]);
#pragma unroll
        for (int n = 0; n < 4; ++n)
            bfv[n] = *reinterpret_cast<const bf16x8*>(&Bs[(wc * 64 + n * 16 + q) * 32 + g * 8]);
#pragma unroll
        for (int m = 0; m < 4; ++m)
#pragma unroll
            for (int n = 0; n < 4; ++n)
                acc[m][n] = __builtin_amdgcn_mfma_f32_16x16x32_bf16(af[m], bfv[n], acc[m][n], 0, 0, 0);
    }
#pragma unroll
    for (int m = 0; m < 4; ++m) {
        const int rbase = m0 + wr * 64 + m * 16 + g * 4;
#pragma unroll
        for (int i = 0; i < 4; ++i) {
            const int row = rbase + i;
#pragma unroll
            for (int n = 0; n < 4; ++n) {
                const int col = n0 + wc * 64 + n * 16 + q;
                out[(size_t)row * CDIM + col] = acc[m][n][i];
            }
        }
    }
}

// ---------------------------------------------------------------------------
extern "C" void kernel_launch(void* const* d_in, const int* in_sizes, int n_in,
                              void* d_out, int out_size, void* d_ws, size_t ws_size,
                              hipStream_t stream) {
    const float* hs = (const float*)d_in[0];
    const float* Wq = (const float*)d_in[1];
    const float* Wk = (const float*)d_in[2];
    const float* Wv = (const float*)d_in[3];
    const float* Wo = (const float*)d_in[4];
    float* out = (float*)d_out;

    bf16* hs_bf = (bf16*)d_ws;                 //  8 MB  (8192x512)
    bf16* wt    = hs_bf + 4194304;             //  2 MB  (4 x 512x512, [fout][fin])
    bf16* Qb    = wt + 4 * 262144;             //  8 MB  [B][H][S][D]
    bf16* Kb    = Qb + 4194304;                //  8 MB  [B][H][S][D]
    bf16* Vb    = Kb + 4194304;                //  8 MB  [B][H][S][D]
    bf16* Vt    = Vb + 4194304;                //  8 MB  [B][H][D][S]
    bf16* Ob    = Vt + 4194304;                //  8 MB  [B][S][H*D]

    k_cvt_hs<<<2048, 256, 0, stream>>>(hs, hs_bf);
    k_wtrans<<<dim3(8, 8, 4), 256, 0, stream>>>(Wq, Wk, Wv, Wo, wt);
    k_gemm_qkv<<<dim3(64, 4, 3), 256, 0, stream>>>(hs_bf, wt, Qb, Kb, Vb);
    k_vtrans<<<dim3(32, 32), 256, 0, stream>>>(Vb, Vt);
    k_attn<<<dim3(32, 32), 256, 0, stream>>>(Qb, Kb, Vt, Ob);
    k_gemm_o<<<dim3(64, 4), 256, 0, stream>>>(Ob, wt + 3 * 262144, out);
}